// Round 9
// baseline (61022.571 us; speedup 1.0000x reference)
//
#include <hip/hip_runtime.h>
#include <hip/hip_bf16.h>

// ---------------------------------------------------------------------------------------
// Fused 2-layer word encoder (f32): embed -> [QKV -> attn -> +Wo,LN -> FF,LN] x2
//   -> masked mean over chars -> scatter to NE. One block per word, 256 threads.
// ---------------------------------------------------------------------------------------
__global__ __launch_bounds__(256) void k_word(
    const int* __restrict__ inputs, const float* __restrict__ char_emb,
    const float* __restrict__ pos_emb,
    const float* __restrict__ Wqkv, const float* __restrict__ Wo,
    const float* __restrict__ ln1s, const float* __restrict__ ln1b,
    const float* __restrict__ W1, const float* __restrict__ W2,
    const float* __restrict__ ln2s, const float* __restrict__ ln2b,
    const int* __restrict__ w2n, const int* __restrict__ wpos,
    float* __restrict__ NE)
{
    const int w = blockIdx.x, tid = threadIdx.x;
    __shared__ float x[16][256];
    __shared__ float b[16 * 1024];
    __shared__ float o[16][256];
    __shared__ float red[16][17];
    __shared__ float mrow[16], srow[16];
    __shared__ int ch[16];

    if (tid < 16) ch[tid] = inputs[w * 16 + tid];
    __syncthreads();

    for (int i = tid; i < 4096; i += 256) {
        int t = i >> 8, d = i & 255;
        x[t][d] = char_emb[(size_t)ch[t] * 256 + d] + pos_emb[t * 256 + d];
    }

    for (int l = 0; l < 2; ++l) {
        const float* wqkv = Wqkv + (size_t)l * 196608;
        const float* wo   = Wo   + (size_t)l * 65536;
        const float* w1   = W1   + (size_t)l * 262144;
        const float* w2   = W2   + (size_t)l * 262144;
        const float* s1 = ln1s + l * 256; const float* b1 = ln1b + l * 256;
        const float* s2 = ln2s + l * 256; const float* b2 = ln2b + l * 256;
        __syncthreads();
        // qkv = x @ wqkv : [16][768]
        for (int i = tid; i < 16 * 768; i += 256) {
            int t = i / 768, n = i % 768;
            float a = 0.f;
            for (int k = 0; k < 256; ++k) a += x[t][k] * wqkv[k * 768 + n];
            b[t * 768 + n] = a;
        }
        __syncthreads();
        // attention (threads 0..127 = (head, query))
        if (tid < 128) {
            int h = tid >> 4, t = tid & 15;
            float q[32];
            for (int d = 0; d < 32; ++d) q[d] = b[t * 768 + h * 32 + d];
            float sc[16], mx = -1e30f;
            for (int s = 0; s < 16; ++s) {
                float dot = 0.f;
                for (int d = 0; d < 32; ++d) dot += q[d] * b[s * 768 + 256 + h * 32 + d];
                dot *= 0.17677669529663687f;     // 1/sqrt(32)
                if (ch[s] == 0) dot = -1e9f;     // key-pad mask (replace, as in ref)
                sc[s] = dot; mx = fmaxf(mx, dot);
            }
            float sum = 0.f;
            for (int s = 0; s < 16; ++s) { sc[s] = expf(sc[s] - mx); sum += sc[s]; }
            float inv = 1.f / sum;
            for (int d = 0; d < 32; ++d) {
                float a = 0.f;
                for (int s = 0; s < 16; ++s) a += sc[s] * b[s * 768 + 512 + h * 32 + d];
                o[t][h * 32 + d] = a * inv;
            }
        }
        __syncthreads();
        // r = x + o @ wo   (r at b+12288, disjoint from qkv region)
        float* r = b + 12288;
        for (int i = tid; i < 4096; i += 256) {
            int t = i >> 8, n = i & 255;
            float a = 0.f;
            for (int k = 0; k < 256; ++k) a += o[t][k] * wo[k * 256 + n];
            r[t * 256 + n] = x[t][n] + a;
        }
        __syncthreads();
        // LN1 -> x
        {
            int row = tid >> 4, ln = tid & 15;
            float s = 0.f;
            for (int j = 0; j < 16; ++j) s += r[row * 256 + ln * 16 + j];
            red[row][ln] = s;
            __syncthreads();
            if (ln == 0) { float m = 0.f; for (int j = 0; j < 16; ++j) m += red[row][j]; mrow[row] = m * (1.f / 256.f); }
            __syncthreads();
            float m = mrow[row], v = 0.f;
            for (int j = 0; j < 16; ++j) { float u = r[row * 256 + ln * 16 + j] - m; v += u * u; }
            red[row][ln] = v;
            __syncthreads();
            if (ln == 0) { float vv = 0.f; for (int j = 0; j < 16; ++j) vv += red[row][j]; srow[row] = rsqrtf(vv * (1.f / 256.f) + 1e-5f); }
            __syncthreads();
            float rs = srow[row];
            for (int j = 0; j < 16; ++j) {
                int d = ln * 16 + j;
                x[row][d] = (r[row * 256 + d] - m) * rs * s1[d] + b1[d];
            }
        }
        __syncthreads();
        // ff hidden = gelu(x @ w1) : [16][1024]
        for (int i = tid; i < 16 * 1024; i += 256) {
            int t = i >> 10, n = i & 1023;
            float a = 0.f;
            for (int k = 0; k < 256; ++k) a += x[t][k] * w1[k * 1024 + n];
            b[t * 1024 + n] = 0.5f * a * (1.f + tanhf(0.7978845608028654f * (a + 0.044715f * a * a * a)));
        }
        __syncthreads();
        // o = hidden @ w2
        for (int i = tid; i < 4096; i += 256) {
            int t = i >> 8, n = i & 255;
            float a = 0.f;
            for (int k = 0; k < 1024; ++k) a += b[t * 1024 + k] * w2[k * 256 + n];
            o[t][n] = a;
        }
        __syncthreads();
        // r2 = x + o (into b[0..4096))
        for (int i = tid; i < 4096; i += 256) {
            int t = i >> 8, n = i & 255;
            b[i] = x[t][n] + o[t][n];
        }
        __syncthreads();
        // LN2 -> x
        {
            int row = tid >> 4, ln = tid & 15;
            float s = 0.f;
            for (int j = 0; j < 16; ++j) s += b[row * 256 + ln * 16 + j];
            red[row][ln] = s;
            __syncthreads();
            if (ln == 0) { float m = 0.f; for (int j = 0; j < 16; ++j) m += red[row][j]; mrow[row] = m * (1.f / 256.f); }
            __syncthreads();
            float m = mrow[row], v = 0.f;
            for (int j = 0; j < 16; ++j) { float u = b[row * 256 + ln * 16 + j] - m; v += u * u; }
            red[row][ln] = v;
            __syncthreads();
            if (ln == 0) { float vv = 0.f; for (int j = 0; j < 16; ++j) vv += red[row][j]; srow[row] = rsqrtf(vv * (1.f / 256.f) + 1e-5f); }
            __syncthreads();
            float rs = srow[row];
            for (int j = 0; j < 16; ++j) {
                int d = ln * 16 + j;
                x[row][d] = (b[row * 256 + d] - m) * rs * s2[d] + b2[d];
            }
        }
    }
    __syncthreads();
    int cnt = 0;
    for (int t = 0; t < 16; ++t) if (ch[t] != 0) ++cnt;
    float inv = (cnt > 0) ? 1.f / (float)cnt : 0.f;
    size_t row = (size_t)w2n[w] * 8 + wpos[w];
    {
        int d = tid;
        float a = 0.f;
        for (int t = 0; t < 16; ++t) if (ch[t] != 0) a += x[t][d];
        NE[row * 256 + d] = a * inv;
    }
}

// ---------------------------------------------------------------------------------------
// Fused 2-layer name encoder + np2-masked mean -> f32 out. One block per name.
// ---------------------------------------------------------------------------------------
__global__ __launch_bounds__(256) void k_name(
    const float* __restrict__ NE,
    const float* __restrict__ Wqkv, const float* __restrict__ Wo,
    const float* __restrict__ ln1s, const float* __restrict__ ln1b,
    const float* __restrict__ W1, const float* __restrict__ W2,
    const float* __restrict__ ln2s, const float* __restrict__ ln2b,
    float* __restrict__ out)
{
    const int nm = blockIdx.x, tid = threadIdx.x;
    __shared__ float x[8][256];
    __shared__ float b[8 * 1024];
    __shared__ float o[8][256];
    __shared__ float red[8][33];
    __shared__ float mrow[8], srow[8];

    for (int i = tid; i < 2048; i += 256) {
        int t = i >> 8, d = i & 255;
        x[t][d] = NE[((size_t)nm * 8 + t) * 256 + d];
    }

    for (int l = 0; l < 2; ++l) {
        const float* wqkv = Wqkv + (size_t)l * 196608;
        const float* wo   = Wo   + (size_t)l * 65536;
        const float* w1   = W1   + (size_t)l * 262144;
        const float* w2   = W2   + (size_t)l * 262144;
        const float* s1 = ln1s + l * 256; const float* b1 = ln1b + l * 256;
        const float* s2 = ln2s + l * 256; const float* b2 = ln2b + l * 256;
        __syncthreads();
        for (int i = tid; i < 8 * 768; i += 256) {
            int t = i / 768, n = i % 768;
            float a = 0.f;
            for (int k = 0; k < 256; ++k) a += x[t][k] * wqkv[k * 768 + n];
            b[t * 768 + n] = a;
        }
        __syncthreads();
        if (tid < 64) {
            int h = tid >> 3, t = tid & 7;
            float q[32];
            for (int d = 0; d < 32; ++d) q[d] = b[t * 768 + h * 32 + d];
            float sc[8], mx = -1e30f;
            for (int s = 0; s < 8; ++s) {
                float dot = 0.f;
                for (int d = 0; d < 32; ++d) dot += q[d] * b[s * 768 + 256 + h * 32 + d];
                dot *= 0.17677669529663687f;
                sc[s] = dot; mx = fmaxf(mx, dot);
            }
            float sum = 0.f;
            for (int s = 0; s < 8; ++s) { sc[s] = expf(sc[s] - mx); sum += sc[s]; }
            float inv = 1.f / sum;
            for (int d = 0; d < 32; ++d) {
                float a = 0.f;
                for (int s = 0; s < 8; ++s) a += sc[s] * b[s * 768 + 512 + h * 32 + d];
                o[t][h * 32 + d] = a * inv;
            }
        }
        __syncthreads();
        float* r = b + 6144;
        for (int i = tid; i < 2048; i += 256) {
            int t = i >> 8, n = i & 255;
            float a = 0.f;
            for (int k = 0; k < 256; ++k) a += o[t][k] * wo[k * 256 + n];
            r[t * 256 + n] = x[t][n] + a;
        }
        __syncthreads();
        {
            int row = tid >> 5, ln = tid & 31;
            float s = 0.f;
            for (int j = 0; j < 8; ++j) s += r[row * 256 + ln * 8 + j];
            red[row][ln] = s;
            __syncthreads();
            if (ln == 0) { float m = 0.f; for (int j = 0; j < 32; ++j) m += red[row][j]; mrow[row] = m * (1.f / 256.f); }
            __syncthreads();
            float m = mrow[row], v = 0.f;
            for (int j = 0; j < 8; ++j) { float u = r[row * 256 + ln * 8 + j] - m; v += u * u; }
            red[row][ln] = v;
            __syncthreads();
            if (ln == 0) { float vv = 0.f; for (int j = 0; j < 32; ++j) vv += red[row][j]; srow[row] = rsqrtf(vv * (1.f / 256.f) + 1e-5f); }
            __syncthreads();
            float rs = srow[row];
            for (int j = 0; j < 8; ++j) {
                int d = ln * 8 + j;
                x[row][d] = (r[row * 256 + d] - m) * rs * s1[d] + b1[d];
            }
        }
        __syncthreads();
        for (int i = tid; i < 8 * 1024; i += 256) {
            int t = i >> 10, n = i & 1023;
            float a = 0.f;
            for (int k = 0; k < 256; ++k) a += x[t][k] * w1[k * 1024 + n];
            b[t * 1024 + n] = 0.5f * a * (1.f + tanhf(0.7978845608028654f * (a + 0.044715f * a * a * a)));
        }
        __syncthreads();
        for (int i = tid; i < 2048; i += 256) {
            int t = i >> 8, n = i & 255;
            float a = 0.f;
            for (int k = 0; k < 1024; ++k) a += b[t * 1024 + k] * w2[k * 256 + n];
            o[t][n] = a;
        }
        __syncthreads();
        for (int i = tid; i < 2048; i += 256) {
            int t = i >> 8, n = i & 255;
            b[i] = x[t][n] + o[t][n];
        }
        __syncthreads();
        {
            int row = tid >> 5, ln = tid & 31;
            float s = 0.f;
            for (int j = 0; j < 8; ++j) s += b[row * 256 + ln * 8 + j];
            red[row][ln] = s;
            __syncthreads();
            if (ln == 0) { float m = 0.f; for (int j = 0; j < 32; ++j) m += red[row][j]; mrow[row] = m * (1.f / 256.f); }
            __syncthreads();
            float m = mrow[row], v = 0.f;
            for (int j = 0; j < 8; ++j) { float u = b[row * 256 + ln * 8 + j] - m; v += u * u; }
            red[row][ln] = v;
            __syncthreads();
            if (ln == 0) { float vv = 0.f; for (int j = 0; j < 32; ++j) vv += red[row][j]; srow[row] = rsqrtf(vv * (1.f / 256.f) + 1e-5f); }
            __syncthreads();
            float rs = srow[row];
            for (int j = 0; j < 8; ++j) {
                int d = ln * 8 + j;
                x[row][d] = (b[row * 256 + d] - m) * rs * s2[d] + b2[d];
            }
        }
    }
    __syncthreads();
    {
        int d = tid;
        float s = 0.f, c = 0.f;
        for (int j = 0; j < 8; ++j) {
            float nev = NE[((size_t)nm * 8 + j) * 256 + d];
            if (nev != 0.f) { s += x[j][d]; c += 1.f; }
        }
        out[(size_t)nm * 256 + d] = (c > 0.f) ? s / c : 0.f;   // f32 output per harness contract
    }
}

// =======================================================================================
extern "C" void kernel_launch(void* const* d_in, const int* in_sizes, int n_in,
                              void* d_out, int out_size, void* d_ws, size_t ws_size,
                              hipStream_t stream) {
    float* out = (float*)d_out;                 // reference output dtype is float32

    const int* inputs    = (const int*)d_in[0];
    const int* w2n       = (const int*)d_in[1];
    const int* wpos      = (const int*)d_in[2];
    const float* char_emb = (const float*)d_in[3];
    const float* pos_emb  = (const float*)d_in[4];
    const float* we_Wqkv = (const float*)d_in[5];
    const float* we_Wo   = (const float*)d_in[6];
    const float* we_ln1s = (const float*)d_in[7];
    const float* we_ln1b = (const float*)d_in[8];
    const float* we_W1   = (const float*)d_in[9];
    const float* we_W2   = (const float*)d_in[10];
    const float* we_ln2s = (const float*)d_in[11];
    const float* we_ln2b = (const float*)d_in[12];
    const float* ne_Wqkv = (const float*)d_in[13];
    const float* ne_Wo   = (const float*)d_in[14];
    const float* ne_ln1s = (const float*)d_in[15];
    const float* ne_ln1b = (const float*)d_in[16];
    const float* ne_W1   = (const float*)d_in[17];
    const float* ne_W2   = (const float*)d_in[18];
    const float* ne_ln2s = (const float*)d_in[19];
    const float* ne_ln2b = (const float*)d_in[20];

    // workspace: NE [2048*8, 256] f32 = 16.8 MB
    float* NE = (float*)d_ws;
    (void)hipMemsetAsync(NE, 0, (size_t)16384 * 256 * 4, stream);

    k_word<<<9216, 256, 0, stream>>>(inputs, char_emb, pos_emb,
                                     we_Wqkv, we_Wo, we_ln1s, we_ln1b,
                                     we_W1, we_W2, we_ln2s, we_ln2b,
                                     w2n, wpos, NE);

    k_name<<<2048, 256, 0, stream>>>(NE,
                                     ne_Wqkv, ne_Wo, ne_ln1s, ne_ln1b,
                                     ne_W1, ne_W2, ne_ln2s, ne_ln2b,
                                     out);
}

// Round 11
// 4353.053 us; speedup vs baseline: 14.0183x; 14.0183x over previous
//
#include <hip/hip_runtime.h>
#include <hip/hip_bf16.h>

using short8 = __attribute__((ext_vector_type(8))) short;
using f32x4  = __attribute__((ext_vector_type(4))) float;

#define DEV __device__ __forceinline__

DEV float bu(unsigned short u) { union { unsigned int i; float f; } z; z.i = (unsigned)u << 16; return z.f; }
DEV unsigned short fb(float f) { __hip_bfloat16 h = __float2bfloat16(f); return *reinterpret_cast<unsigned short*>(&h); }

// ---------------- weight prep: WT[n][k] = bf16(W[k][n]) ----------------
__global__ void k_wt(const float* __restrict__ W, unsigned short* __restrict__ WT, int K, int N) {
    int i = blockIdx.x * 256 + threadIdx.x;
    if (i >= N * K) return;
    int n = i / K, k = i % K;
    WT[i] = fb(W[(size_t)k * N + n]);
}

// ---------------------------------------------------------------------------------------
// Per-wave MFMA GEMM slab: D[16][NT*16] = A[16][K](bf16 LDS, ldA padded) @ B[N][K]^T
// (bf16 global, row-major transposed weights). v_mfma_f32_16x16x32_bf16.
// A-frag: row=l&15, k=(l>>4)*8+j (same contiguous-k map for B => layout-proof).
// D: row=(l>>4)*4+r, col=l&15 [m89-verified].
// ---------------------------------------------------------------------------------------
template<int NT, int KG, bool GEL, bool BOUT>
DEV void gemm16(const unsigned short* __restrict__ A, int ldA,
                const unsigned short* __restrict__ B, int K,
                float* outF, unsigned short* outB, int ldo,
                int nt0, int lane)
{
    const int fl = lane & 15, fh = lane >> 4;
    f32x4 acc[NT] = {};
#pragma unroll 4
    for (int kg = 0; kg < KG; ++kg) {
        short8 a = *(const short8*)(A + fl * ldA + kg * 32 + fh * 8);
#pragma unroll
        for (int i = 0; i < NT; ++i) {
            short8 b = *(const short8*)(B + (size_t)((nt0 + i) * 16 + fl) * K + kg * 32 + fh * 8);
            acc[i] = __builtin_amdgcn_mfma_f32_16x16x32_bf16(a, b, acc[i], 0, 0, 0);
        }
    }
    const int r0 = fh * 4;
#pragma unroll
    for (int i = 0; i < NT; ++i) {
        int n0 = (nt0 + i) * 16;
#pragma unroll
        for (int r = 0; r < 4; ++r) {
            float v = acc[i][r];
            if (GEL) v = 0.5f * v * (1.f + tanhf(0.7978845608028654f * (v + 0.044715f * v * v * v)));
            if (BOUT) outB[(r0 + r) * ldo + n0 + fl] = fb(v);
            else      outF[(r0 + r) * ldo + n0 + fl] = v;
        }
    }
}

// LN over rows of r (=[16][256] linear f32) -> x (f32) and xb (bf16, ld 264); rows>=T forced 0.
template<int T>
DEV void ln_pass(const float* __restrict__ r, const float* __restrict__ s1, const float* __restrict__ b1,
                 float x[16][256], unsigned short* __restrict__ xb,
                 float red[16][17], float* mrow, float* srow, int tid)
{
    int row = tid >> 4, ln = tid & 15;
    float s = 0.f;
#pragma unroll
    for (int j = 0; j < 16; ++j) s += r[row * 256 + ln * 16 + j];
    red[row][ln] = s;
    __syncthreads();
    if (ln == 0) { float m = 0.f; for (int j = 0; j < 16; ++j) m += red[row][j]; mrow[row] = m * (1.f / 256.f); }
    __syncthreads();
    float m = mrow[row], v = 0.f;
#pragma unroll
    for (int j = 0; j < 16; ++j) { float u = r[row * 256 + ln * 16 + j] - m; v += u * u; }
    red[row][ln] = v;
    __syncthreads();
    if (ln == 0) { float vv = 0.f; for (int j = 0; j < 16; ++j) vv += red[row][j]; srow[row] = rsqrtf(vv * (1.f / 256.f) + 1e-5f); }
    __syncthreads();
    float rs = srow[row];
#pragma unroll
    for (int j = 0; j < 16; ++j) {
        int d = ln * 16 + j;
        float o = (r[row * 256 + d] - m) * rs * s1[d] + b1[d];
        if (row >= T) o = 0.f;
        x[row][d] = o;
        xb[row * 264 + d] = fb(o);
    }
}

// ---------------------------------------------------------------------------------------
// Fused 2-layer encoder, MFMA GEMMs. One block per word/name, 256 threads (4 waves).
// WORD: embed chars -> ... -> masked mean -> scatter NE.  !WORD: NE -> ... -> np2 mean -> out.
// ---------------------------------------------------------------------------------------
template<int T, bool WORD>
__global__ __launch_bounds__(256, 2) void k_enc(
    const int* __restrict__ inputs,
    const float* __restrict__ char_emb, const float* __restrict__ pos_emb,
    const unsigned short* __restrict__ qkvT, const unsigned short* __restrict__ woT,
    const unsigned short* __restrict__ w1T,  const unsigned short* __restrict__ w2T,
    const float* __restrict__ ln1s, const float* __restrict__ ln1b,
    const float* __restrict__ ln2s, const float* __restrict__ ln2b,
    const int* __restrict__ w2n, const int* __restrict__ wpos,
    float* __restrict__ NE, float* __restrict__ out)
{
    const int blk = blockIdx.x, tid = threadIdx.x;
    const int lane = tid & 63, wid = tid >> 6;
    __shared__ float x[16][256];                                   // residual stream (f32)
    __shared__ float scb[16][256];                                 // gemm f32 out / LN input
    __shared__ __attribute__((aligned(16))) unsigned short xb[16 * 264];   // bf16 A operand (+8 pad)
    __shared__ __attribute__((aligned(16))) unsigned short U[16512];       // qkv[16][768]+o[16][264] | hidden[16][1032]
    __shared__ float red[16][17];
    __shared__ float mrow[16], srow[16];
    __shared__ int ch[16];
    float* scl = &scb[0][0];
    float* xl  = &x[0][0];

    if (WORD) {
        if (tid < 16) ch[tid] = inputs[blk * 16 + tid];
        __syncthreads();
        for (int i = tid; i < 4096; i += 256) {
            int t = i >> 8, d = i & 255;
            float v = char_emb[(size_t)ch[t] * 256 + d] + pos_emb[t * 256 + d];
            x[t][d] = v; xb[t * 264 + d] = fb(v);
        }
    } else {
        for (int i = tid; i < 4096; i += 256) {
            int t = i >> 8, d = i & 255;
            float v = (t < T) ? NE[((size_t)blk * 8 + t) * 256 + d] : 0.f;
            x[t][d] = v; xb[t * 264 + d] = fb(v);
        }
    }
    __syncthreads();

    for (int l = 0; l < 2; ++l) {
        const unsigned short* wqkv = qkvT + (size_t)l * 196608;
        const unsigned short* wwo  = woT  + (size_t)l * 65536;
        const unsigned short* ww1  = w1T  + (size_t)l * 262144;
        const unsigned short* ww2  = w2T  + (size_t)l * 262144;

        // ---- QKV: U[16][768](bf16) = xb @ Wqkv ----
        gemm16<6, 8, false, true>(xb, 264, wqkv, 256, nullptr, U, 768, wid * 6, lane);
        gemm16<6, 8, false, true>(xb, 264, wqkv, 256, nullptr, U, 768, 24 + wid * 6, lane);
        __syncthreads();

        // ---- attention (threads 0..8T-1) + zero o rows T..15 ----
        unsigned short* o = U + 12288;                             // [16][264] bf16
        if (T < 16) for (int i = tid; i < (16 - T) * 264; i += 256) o[T * 264 + i] = 0;
        if (tid < 8 * T) {
            int h = tid / T, t = tid % T;
            float q[32];
#pragma unroll
            for (int d = 0; d < 32; ++d) q[d] = bu(U[t * 768 + h * 32 + d]);
            float p[T], mx = -1e30f;
#pragma unroll
            for (int s = 0; s < T; ++s) {
                float dot = 0.f;
#pragma unroll
                for (int d = 0; d < 32; ++d) dot += q[d] * bu(U[s * 768 + 256 + h * 32 + d]);
                dot *= 0.17677669529663687f;                       // 1/sqrt(32)
                if (WORD && ch[s] == 0) dot = -1e9f;               // replace, as in reference
                p[s] = dot; mx = fmaxf(mx, dot);
            }
            float sum = 0.f;
#pragma unroll
            for (int s = 0; s < T; ++s) { p[s] = expf(p[s] - mx); sum += p[s]; }
            float inv = 1.f / sum;
#pragma unroll
            for (int d = 0; d < 32; ++d) {
                float a = 0.f;
#pragma unroll
                for (int s = 0; s < T; ++s) a += p[s] * bu(U[s * 768 + 512 + h * 32 + d]);
                o[t * 264 + h * 32 + d] = fb(a * inv);
            }
        }
        __syncthreads();

        // ---- Wo: scb = o @ Wo ----
        gemm16<4, 8, false, false>(o, 264, wwo, 256, scl, nullptr, 256, wid * 4, lane);
        __syncthreads();
        for (int i = tid; i < 4096; i += 256) scl[i] += xl[i];     // + residual
        __syncthreads();
        ln_pass<T>(scl, ln1s + l * 256, ln1b + l * 256, x, xb, red, mrow, srow, tid);
        __syncthreads();

        // ---- FF1: U[16][1032](bf16) = gelu(xb @ W1) ----
        gemm16<8, 8, true, true>(xb, 264, ww1, 256, nullptr, U, 1032, wid * 8, lane);
        gemm16<8, 8, true, true>(xb, 264, ww1, 256, nullptr, U, 1032, 32 + wid * 8, lane);
        __syncthreads();

        // ---- FF2: scb = hidden @ W2 ----
        gemm16<4, 32, false, false>(U, 1032, ww2, 1024, scl, nullptr, 256, wid * 4, lane);
        __syncthreads();
        for (int i = tid; i < 4096; i += 256) scl[i] += xl[i];
        __syncthreads();
        ln_pass<T>(scl, ln2s + l * 256, ln2b + l * 256, x, xb, red, mrow, srow, tid);
        __syncthreads();
    }

    if (WORD) {
        int cnt = 0;
#pragma unroll
        for (int t = 0; t < 16; ++t) if (ch[t] != 0) ++cnt;
        float inv = 1.f / (float)cnt;
        size_t row = (size_t)w2n[blk] * 8 + wpos[blk];
        int d = tid;
        float a = 0.f;
#pragma unroll
        for (int t = 0; t < 16; ++t) if (ch[t] != 0) a += x[t][d];
        NE[row * 256 + d] = a * inv;
    } else {
        int d = tid;
        float s = 0.f, c = 0.f;
#pragma unroll
        for (int j = 0; j < T; ++j) {
            float nev = NE[((size_t)blk * 8 + j) * 256 + d];
            if (nev != 0.f) { s += x[j][d]; c += 1.f; }
        }
        out[(size_t)blk * 256 + d] = (c > 0.f) ? s / c : 0.f;
    }
}

// =======================================================================================
extern "C" void kernel_launch(void* const* d_in, const int* in_sizes, int n_in,
                              void* d_out, int out_size, void* d_ws, size_t ws_size,
                              hipStream_t stream) {
    float* out = (float*)d_out;                                    // reference output: float32

    const int* inputs    = (const int*)d_in[0];
    const int* w2n       = (const int*)d_in[1];
    const int* wpos      = (const int*)d_in[2];
    const float* char_emb = (const float*)d_in[3];
    const float* pos_emb  = (const float*)d_in[4];
    const float* we_Wqkv = (const float*)d_in[5];
    const float* we_Wo   = (const float*)d_in[6];
    const float* we_ln1s = (const float*)d_in[7];
    const float* we_ln1b = (const float*)d_in[8];
    const float* we_W1   = (const float*)d_in[9];
    const float* we_W2   = (const float*)d_in[10];
    const float* we_ln2s = (const float*)d_in[11];
    const float* we_ln2b = (const float*)d_in[12];
    const float* ne_Wqkv = (const float*)d_in[13];
    const float* ne_Wo   = (const float*)d_in[14];
    const float* ne_ln1s = (const float*)d_in[15];
    const float* ne_ln1b = (const float*)d_in[16];
    const float* ne_W1   = (const float*)d_in[17];
    const float* ne_W2   = (const float*)d_in[18];
    const float* ne_ln2s = (const float*)d_in[19];
    const float* ne_ln2b = (const float*)d_in[20];

    // ---- workspace: NE (f32, 16.8MB) + transposed bf16 weights (6.3MB) ----
    char* ws = (char*)d_ws;
    size_t off = 0;
    auto alloc = [&](size_t bytes) { void* p = ws + off; off += (bytes + 255) & ~(size_t)255; return p; };
    float* NE = (float*)alloc((size_t)16384 * 256 * 4);
    unsigned short* qkvT_we = (unsigned short*)alloc((size_t)2 * 196608 * 2);
    unsigned short* woT_we  = (unsigned short*)alloc((size_t)2 * 65536 * 2);
    unsigned short* w1T_we  = (unsigned short*)alloc((size_t)2 * 262144 * 2);
    unsigned short* w2T_we  = (unsigned short*)alloc((size_t)2 * 262144 * 2);
    unsigned short* qkvT_ne = (unsigned short*)alloc((size_t)2 * 196608 * 2);
    unsigned short* woT_ne  = (unsigned short*)alloc((size_t)2 * 65536 * 2);
    unsigned short* w1T_ne  = (unsigned short*)alloc((size_t)2 * 262144 * 2);
    unsigned short* w2T_ne  = (unsigned short*)alloc((size_t)2 * 262144 * 2);

    for (int l = 0; l < 2; ++l) {
        k_wt<<<(196608 + 255) / 256, 256, 0, stream>>>(we_Wqkv + (size_t)l * 196608, qkvT_we + (size_t)l * 196608, 256, 768);
        k_wt<<<(65536  + 255) / 256, 256, 0, stream>>>(we_Wo   + (size_t)l * 65536,  woT_we  + (size_t)l * 65536,  256, 256);
        k_wt<<<(262144 + 255) / 256, 256, 0, stream>>>(we_W1   + (size_t)l * 262144, w1T_we  + (size_t)l * 262144, 256, 1024);
        k_wt<<<(262144 + 255) / 256, 256, 0, stream>>>(we_W2   + (size_t)l * 262144, w2T_we  + (size_t)l * 262144, 1024, 256);
        k_wt<<<(196608 + 255) / 256, 256, 0, stream>>>(ne_Wqkv + (size_t)l * 196608, qkvT_ne + (size_t)l * 196608, 256, 768);
        k_wt<<<(65536  + 255) / 256, 256, 0, stream>>>(ne_Wo   + (size_t)l * 65536,  woT_ne  + (size_t)l * 65536,  256, 256);
        k_wt<<<(262144 + 255) / 256, 256, 0, stream>>>(ne_W1   + (size_t)l * 262144, w1T_ne  + (size_t)l * 262144, 256, 1024);
        k_wt<<<(262144 + 255) / 256, 256, 0, stream>>>(ne_W2   + (size_t)l * 262144, w2T_ne  + (size_t)l * 262144, 1024, 256);
    }

    (void)hipMemsetAsync(NE, 0, (size_t)16384 * 256 * 4, stream);  // pad slots must be zero

    k_enc<16, true><<<9216, 256, 0, stream>>>(inputs, char_emb, pos_emb,
                                              qkvT_we, woT_we, w1T_we, w2T_we,
                                              we_ln1s, we_ln1b, we_ln2s, we_ln2b,
                                              w2n, wpos, NE, nullptr);

    k_enc<8, false><<<2048, 256, 0, stream>>>(nullptr, nullptr, nullptr,
                                              qkvT_ne, woT_ne, w1T_ne, w2T_ne,
                                              ne_ln1s, ne_ln1b, ne_ln2s, ne_ln2b,
                                              nullptr, nullptr, NE, out);
}

// Round 16
// 2205.310 us; speedup vs baseline: 27.6707x; 1.9739x over previous
//
#include <hip/hip_runtime.h>
#include <hip/hip_bf16.h>

using short8 = __attribute__((ext_vector_type(8))) short;
using f32x4  = __attribute__((ext_vector_type(4))) float;

#define DEV __device__ __forceinline__
#define LDB 264

DEV float bu(unsigned short u) { union { unsigned int i; float f; } z; z.i = (unsigned)u << 16; return z.f; }
DEV unsigned short fb(float f) { __hip_bfloat16 h = __float2bfloat16(f); return *reinterpret_cast<unsigned short*>(&h); }

// ---------------- weight prep: WT[n][k] = bf16(W[k][n]) ----------------
__global__ void k_wt(const float* __restrict__ W, unsigned short* __restrict__ WT, int K, int N) {
    int i = blockIdx.x * 256 + threadIdx.x;
    if (i >= N * K) return;
    int n = i / K, k = i % K;
    WT[i] = fb(W[(size_t)k * N + n]);
}

// ======================= R11 kernels (hardware-proven) — NAME stage =====================
template<int NT, int KG, bool GEL, bool BOUT>
DEV void gemm16(const unsigned short* __restrict__ A, int ldA,
                const unsigned short* __restrict__ B, int K,
                float* outF, unsigned short* outB, int ldo,
                int nt0, int lane)
{
    const int fl = lane & 15, fh = lane >> 4;
    f32x4 acc[NT] = {};
#pragma unroll 4
    for (int kg = 0; kg < KG; ++kg) {
        short8 a = *(const short8*)(A + fl * ldA + kg * 32 + fh * 8);
#pragma unroll
        for (int i = 0; i < NT; ++i) {
            short8 b = *(const short8*)(B + (size_t)((nt0 + i) * 16 + fl) * K + kg * 32 + fh * 8);
            acc[i] = __builtin_amdgcn_mfma_f32_16x16x32_bf16(a, b, acc[i], 0, 0, 0);
        }
    }
    const int r0 = fh * 4;
#pragma unroll
    for (int i = 0; i < NT; ++i) {
        int n0 = (nt0 + i) * 16;
#pragma unroll
        for (int r = 0; r < 4; ++r) {
            float v = acc[i][r];
            if (GEL) v = 0.5f * v * (1.f + tanhf(0.7978845608028654f * (v + 0.044715f * v * v * v)));
            if (BOUT) outB[(r0 + r) * ldo + n0 + fl] = fb(v);
            else      outF[(r0 + r) * ldo + n0 + fl] = v;
        }
    }
}

template<int T>
DEV void ln_pass(const float* __restrict__ r, const float* __restrict__ s1, const float* __restrict__ b1,
                 float x[16][256], unsigned short* __restrict__ xb,
                 float red[16][17], float* mrow, float* srow, int tid)
{
    int row = tid >> 4, ln = tid & 15;
    float s = 0.f;
#pragma unroll
    for (int j = 0; j < 16; ++j) s += r[row * 256 + ln * 16 + j];
    red[row][ln] = s;
    __syncthreads();
    if (ln == 0) { float m = 0.f; for (int j = 0; j < 16; ++j) m += red[row][j]; mrow[row] = m * (1.f / 256.f); }
    __syncthreads();
    float m = mrow[row], v = 0.f;
#pragma unroll
    for (int j = 0; j < 16; ++j) { float u = r[row * 256 + ln * 16 + j] - m; v += u * u; }
    red[row][ln] = v;
    __syncthreads();
    if (ln == 0) { float vv = 0.f; for (int j = 0; j < 16; ++j) vv += red[row][j]; srow[row] = rsqrtf(vv * (1.f / 256.f) + 1e-5f); }
    __syncthreads();
    float rs = srow[row];
#pragma unroll
    for (int j = 0; j < 16; ++j) {
        int d = ln * 16 + j;
        float o = (r[row * 256 + d] - m) * rs * s1[d] + b1[d];
        if (row >= T) o = 0.f;
        x[row][d] = o;
        xb[row * 264 + d] = fb(o);
    }
}

template<int T, bool WORD>
__global__ __launch_bounds__(256, 2) void k_enc_ref(
    const int* __restrict__ inputs,
    const float* __restrict__ char_emb, const float* __restrict__ pos_emb,
    const unsigned short* __restrict__ qkvT, const unsigned short* __restrict__ woT,
    const unsigned short* __restrict__ w1T,  const unsigned short* __restrict__ w2T,
    const float* __restrict__ ln1s, const float* __restrict__ ln1b,
    const float* __restrict__ ln2s, const float* __restrict__ ln2b,
    const int* __restrict__ w2n, const int* __restrict__ wpos,
    float* __restrict__ NE, float* __restrict__ out)
{
    const int blk = blockIdx.x, tid = threadIdx.x;
    const int lane = tid & 63, wid = tid >> 6;
    __shared__ float x[16][256];
    __shared__ float scb[16][256];
    __shared__ __attribute__((aligned(16))) unsigned short xb[16 * 264];
    __shared__ __attribute__((aligned(16))) unsigned short U[16512];
    __shared__ float red[16][17];
    __shared__ float mrow[16], srow[16];
    __shared__ int ch[16];
    float* scl = &scb[0][0];
    float* xl  = &x[0][0];

    if (WORD) {
        if (tid < 16) ch[tid] = inputs[blk * 16 + tid];
        __syncthreads();
        for (int i = tid; i < 4096; i += 256) {
            int t = i >> 8, d = i & 255;
            float v = char_emb[(size_t)ch[t] * 256 + d] + pos_emb[t * 256 + d];
            x[t][d] = v; xb[t * 264 + d] = fb(v);
        }
    } else {
        for (int i = tid; i < 4096; i += 256) {
            int t = i >> 8, d = i & 255;
            float v = (t < T) ? NE[((size_t)blk * 8 + t) * 256 + d] : 0.f;
            x[t][d] = v; xb[t * 264 + d] = fb(v);
        }
    }
    __syncthreads();

    for (int l = 0; l < 2; ++l) {
        const unsigned short* wqkv = qkvT + (size_t)l * 196608;
        const unsigned short* wwo  = woT  + (size_t)l * 65536;
        const unsigned short* ww1  = w1T  + (size_t)l * 262144;
        const unsigned short* ww2  = w2T  + (size_t)l * 262144;

        gemm16<6, 8, false, true>(xb, 264, wqkv, 256, nullptr, U, 768, wid * 6, lane);
        gemm16<6, 8, false, true>(xb, 264, wqkv, 256, nullptr, U, 768, 24 + wid * 6, lane);
        __syncthreads();

        unsigned short* o = U + 12288;
        if (T < 16) for (int i = tid; i < (16 - T) * 264; i += 256) o[T * 264 + i] = 0;
        if (tid < 8 * T) {
            int h = tid / T, t = tid % T;
            float q[32];
#pragma unroll
            for (int d = 0; d < 32; ++d) q[d] = bu(U[t * 768 + h * 32 + d]);
            float p[T], mx = -1e30f;
#pragma unroll
            for (int s = 0; s < T; ++s) {
                float dot = 0.f;
#pragma unroll
                for (int d = 0; d < 32; ++d) dot += q[d] * bu(U[s * 768 + 256 + h * 32 + d]);
                dot *= 0.17677669529663687f;
                if (WORD && ch[s] == 0) dot = -1e9f;
                p[s] = dot; mx = fmaxf(mx, dot);
            }
            float sum = 0.f;
#pragma unroll
            for (int s = 0; s < T; ++s) { p[s] = expf(p[s] - mx); sum += p[s]; }
            float inv = 1.f / sum;
#pragma unroll
            for (int d = 0; d < 32; ++d) {
                float a = 0.f;
#pragma unroll
                for (int s = 0; s < T; ++s) a += p[s] * bu(U[s * 768 + 512 + h * 32 + d]);
                o[t * 264 + h * 32 + d] = fb(a * inv);
            }
        }
        __syncthreads();

        gemm16<4, 8, false, false>(o, 264, wwo, 256, scl, nullptr, 256, wid * 4, lane);
        __syncthreads();
        for (int i = tid; i < 4096; i += 256) scl[i] += xl[i];
        __syncthreads();
        ln_pass<T>(scl, ln1s + l * 256, ln1b + l * 256, x, xb, red, mrow, srow, tid);
        __syncthreads();

        gemm16<8, 8, true, true>(xb, 264, ww1, 256, nullptr, U, 1032, wid * 8, lane);
        gemm16<8, 8, true, true>(xb, 264, ww1, 256, nullptr, U, 1032, 32 + wid * 8, lane);
        __syncthreads();

        gemm16<4, 32, false, false>(U, 1032, ww2, 1024, scl, nullptr, 256, wid * 4, lane);
        __syncthreads();
        for (int i = tid; i < 4096; i += 256) scl[i] += xl[i];
        __syncthreads();
        ln_pass<T>(scl, ln2s + l * 256, ln2b + l * 256, x, xb, red, mrow, srow, tid);
        __syncthreads();
    }

    if (WORD) {
        int cnt = 0;
#pragma unroll
        for (int t = 0; t < 16; ++t) if (ch[t] != 0) ++cnt;
        float inv = 1.f / (float)cnt;
        size_t row = (size_t)w2n[blk] * 8 + wpos[blk];
        int d = tid;
        float a = 0.f;
#pragma unroll
        for (int t = 0; t < 16; ++t) if (ch[t] != 0) a += x[t][d];
        NE[row * 256 + d] = a * inv;
    } else {
        int d = tid;
        float s = 0.f, c = 0.f;
#pragma unroll
        for (int j = 0; j < T; ++j) {
            float nev = NE[((size_t)blk * 8 + j) * 256 + d];
            if (nev != 0.f) { s += x[j][d]; c += 1.f; }
        }
        out[(size_t)blk * 256 + d] = (c > 0.f) ? s / c : 0.f;
    }
}

// ======= M=64 batched WORD kernel, f32 residual in REGISTERS (R11 precision parity) =====
// Thread (wid 0..7, lane: fl=lane&15, fh=lane>>4) owns cells:
//   rows m*16+fh*4+r (m,r in 0..3), cols (wid*2+i)*16+fl (i in 0..1)  -> xr[m][r][i] f32
// which are exactly its MFMA D-fragment positions (mm64 acc[i][m][r]).
template<int NT, int KG>
DEV void mm64(const unsigned short* __restrict__ A, const unsigned short* __restrict__ B,
              int ldB, int koff, f32x4 acc[NT][4], int nt0, int lane)
{
    const int fl = lane & 15, fh = lane >> 4;
#pragma unroll
    for (int kg = 0; kg < KG; ++kg) {
        short8 b[NT];
#pragma unroll
        for (int i = 0; i < NT; ++i)
            b[i] = *(const short8*)(B + (size_t)((nt0 + i) * 16 + fl) * ldB + koff + kg * 32 + fh * 8);
        short8 a[4];
#pragma unroll
        for (int m = 0; m < 4; ++m)
            a[m] = *(const short8*)(A + (m * 16 + fl) * LDB + kg * 32 + fh * 8);
#pragma unroll
        for (int i = 0; i < NT; ++i)
#pragma unroll
            for (int m = 0; m < 4; ++m)
                acc[i][m] = __builtin_amdgcn_mfma_f32_16x16x32_bf16(a[m], b[i], acc[i][m], 0, 0, 0);
    }
}

template<int NT, bool GEL>
DEV void store_bf16(f32x4 acc[NT][4], unsigned short* __restrict__ D, int nt0, int lane) {
    const int fl = lane & 15, r0 = (lane >> 4) * 4;
#pragma unroll
    for (int i = 0; i < NT; ++i)
#pragma unroll
        for (int m = 0; m < 4; ++m)
#pragma unroll
            for (int r = 0; r < 4; ++r) {
                float v = acc[i][m][r];
                if (GEL) v = 0.5f * v * (1.f + tanhf(0.7978845608028654f * (v + 0.044715f * v * v * v)));
                D[(m * 16 + r0 + r) * LDB + (nt0 + i) * 16 + fl] = fb(v);
            }
}

// f32 LayerNorm over register-resident xr; stats via shfl + red[64][8]; writes bf16 xb.
DEV void ln_reg(float xr[4][4][2], const float* __restrict__ s, const float* __restrict__ b,
                unsigned short* __restrict__ xb, float red[64][8],
                float* mrow, float* srow, int tid, int fl, int fh, int wid)
{
    // mean partials
    float ps[4][4];
#pragma unroll
    for (int m = 0; m < 4; ++m)
#pragma unroll
        for (int r = 0; r < 4; ++r) {
            float v = xr[m][r][0] + xr[m][r][1];
#pragma unroll
            for (int off = 8; off >= 1; off >>= 1) v += __shfl_xor(v, off, 64);
            ps[m][r] = v;                        // sum over this wave's 32 cols of the row
        }
    if (fl == 0)
#pragma unroll
        for (int m = 0; m < 4; ++m)
#pragma unroll
            for (int r = 0; r < 4; ++r) red[m * 16 + fh * 4 + r][wid] = ps[m][r];
    __syncthreads();
    if (tid < 64) {
        float sum = 0.f;
#pragma unroll
        for (int j = 0; j < 8; ++j) sum += red[tid][j];
        mrow[tid] = sum * (1.f / 256.f);
    }
    __syncthreads();
    // variance partials
#pragma unroll
    for (int m = 0; m < 4; ++m)
#pragma unroll
        for (int r = 0; r < 4; ++r) {
            float mu = mrow[m * 16 + fh * 4 + r];
            float d0 = xr[m][r][0] - mu, d1 = xr[m][r][1] - mu;
            float v = d0 * d0 + d1 * d1;
#pragma unroll
            for (int off = 8; off >= 1; off >>= 1) v += __shfl_xor(v, off, 64);
            ps[m][r] = v;
        }
    if (fl == 0)
#pragma unroll
        for (int m = 0; m < 4; ++m)
#pragma unroll
            for (int r = 0; r < 4; ++r) red[m * 16 + fh * 4 + r][wid] = ps[m][r];
    __syncthreads();
    if (tid < 64) {
        float sum = 0.f;
#pragma unroll
        for (int j = 0; j < 8; ++j) sum += red[tid][j];
        srow[tid] = rsqrtf(sum * (1.f / 256.f) + 1e-5f);
    }
    __syncthreads();
    // normalize (f32 in regs) + bf16 copy for GEMM A-operand
    float sc[2], bc[2];
#pragma unroll
    for (int i = 0; i < 2; ++i) { int c = (wid * 2 + i) * 16 + fl; sc[i] = s[c]; bc[i] = b[c]; }
#pragma unroll
    for (int m = 0; m < 4; ++m)
#pragma unroll
        for (int r = 0; r < 4; ++r) {
            int row = m * 16 + fh * 4 + r;
            float mu = mrow[row], rs = srow[row];
#pragma unroll
            for (int i = 0; i < 2; ++i) {
                float v = (xr[m][r][i] - mu) * rs * sc[i] + bc[i];
                xr[m][r][i] = v;
                xb[row * LDB + (wid * 2 + i) * 16 + fl] = fb(v);
            }
        }
    __syncthreads();
}

__global__ __launch_bounds__(512, 1) void k_word_v2(
    const int* __restrict__ inputs,
    const float* __restrict__ char_emb, const float* __restrict__ pos_emb,
    const unsigned short* __restrict__ qkvT, const unsigned short* __restrict__ woT,
    const unsigned short* __restrict__ w1T,  const unsigned short* __restrict__ w2T,
    const float* __restrict__ ln1s, const float* __restrict__ ln1b,
    const float* __restrict__ ln2s, const float* __restrict__ ln2b,
    const int* __restrict__ w2n, const int* __restrict__ wpos,
    float* __restrict__ NE)
{
    const int blk = blockIdx.x, tid = threadIdx.x;
    const int lane = tid & 63, wid = tid >> 6;
    const int fl = lane & 15, fh = lane >> 4;
    __shared__ __attribute__((aligned(16))) unsigned short xb[64 * LDB];  // bf16 A-operand
    __shared__ __attribute__((aligned(16))) unsigned short S1[64 * LDB];  // Q / V / ff-hidden
    __shared__ __attribute__((aligned(16))) unsigned short S2[64 * LDB];  // K / attn-out
    __shared__ float red[64][8];
    __shared__ float mrow[64], srow[64];
    __shared__ int ch[64];

    // attention thread mapping (T=16): 4 words x 8 heads x 16 queries
    const int wl = tid >> 7, hh = (tid >> 4) & 7, tt = tid & 15;
    const int arow = wl * 16 + tt;

    float xr[4][4][2];   // f32 residual stream, this thread's fragment cells

    if (tid < 64) ch[tid] = inputs[blk * 64 + tid];
    __syncthreads();
#pragma unroll
    for (int m = 0; m < 4; ++m)
#pragma unroll
        for (int r = 0; r < 4; ++r) {
            int row = m * 16 + fh * 4 + r;
#pragma unroll
            for (int i = 0; i < 2; ++i) {
                int col = (wid * 2 + i) * 16 + fl;
                float v = char_emb[(size_t)ch[row] * 256 + col] + pos_emb[(row & 15) * 256 + col];
                xr[m][r][i] = v;
                xb[row * LDB + col] = fb(v);
            }
        }
    __syncthreads();

    for (int l = 0; l < 2; ++l) {
        const unsigned short* wq = qkvT + (size_t)l * 196608;
        const unsigned short* wk = wq + 65536;
        const unsigned short* wv = wq + 131072;
        const unsigned short* wo = woT + (size_t)l * 65536;
        const unsigned short* w1 = w1T + (size_t)l * 262144;
        const unsigned short* w2 = w2T + (size_t)l * 262144;

        // ---- Q->S1, K->S2 ----
        { f32x4 acc[2][4] = {}; mm64<2, 8>(xb, wq, 256, 0, acc, wid * 2, lane); store_bf16<2, false>(acc, S1, wid * 2, lane); }
        { f32x4 acc[2][4] = {}; mm64<2, 8>(xb, wk, 256, 0, acc, wid * 2, lane); store_bf16<2, false>(acc, S2, wid * 2, lane); }
        __syncthreads();

        // ---- q -> regs; scores+softmax from S2(K) ----
        float q[32], p[16];
        {
#pragma unroll
            for (int d = 0; d < 32; ++d) q[d] = bu(S1[arow * LDB + hh * 32 + d]);
            float mx = -1e30f;
#pragma unroll
            for (int s = 0; s < 16; ++s) {
                float dot = 0.f;
#pragma unroll
                for (int d = 0; d < 32; ++d) dot += q[d] * bu(S2[(wl * 16 + s) * LDB + hh * 32 + d]);
                dot *= 0.17677669529663687f;             // 1/sqrt(32)
                if (ch[wl * 16 + s] == 0) dot = -1e9f;   // key-pad mask (replace, as in ref)
                p[s] = dot; mx = fmaxf(mx, dot);
            }
            float sum = 0.f;
#pragma unroll
            for (int s = 0; s < 16; ++s) { p[s] = expf(p[s] - mx); sum += p[s]; }
            float inv = 1.f / sum;
#pragma unroll
            for (int s = 0; s < 16; ++s) p[s] *= inv;
        }
        __syncthreads();                                  // all q loaded; S1 free

        // ---- V->S1 (overwrites Q; q already in regs) ----
        { f32x4 acc[2][4] = {}; mm64<2, 8>(xb, wv, 256, 0, acc, wid * 2, lane); store_bf16<2, false>(acc, S1, wid * 2, lane); }
        __syncthreads();

        // ---- PV from S1(V) -> o into S2 (K dead; own-cell writes race-free) ----
#pragma unroll
        for (int d = 0; d < 32; ++d) {
            float a = 0.f;
#pragma unroll
            for (int s = 0; s < 16; ++s) a += p[s] * bu(S1[(wl * 16 + s) * LDB + hh * 32 + d]);
            S2[arow * LDB + hh * 32 + d] = fb(a);
        }
        __syncthreads();

        // ---- Wo: S2(o) @ wo ; residual add in f32 regs; LN1 ----
        { f32x4 acc[2][4] = {}; mm64<2, 8>(S2, wo, 256, 0, acc, wid * 2, lane);
#pragma unroll
          for (int i = 0; i < 2; ++i)
#pragma unroll
              for (int m = 0; m < 4; ++m)
#pragma unroll
                  for (int r = 0; r < 4; ++r) xr[m][r][i] += acc[i][m][r]; }
        __syncthreads();
        ln_reg(xr, ln1s + l * 256, ln1b + l * 256, xb, red, mrow, srow, tid, fl, fh, wid);

        // ---- FF: 4 hidden chunks; FF2 accumulates f32; residual; LN2 ----
        {
            f32x4 acc2[2][4] = {};
            for (int c = 0; c < 4; ++c) {
                f32x4 acc1[2][4] = {};
                mm64<2, 8>(xb, w1 + (size_t)c * 65536, 256, 0, acc1, wid * 2, lane);
                store_bf16<2, true>(acc1, S1, wid * 2, lane);      // gelu(hidden chunk)
                __syncthreads();
                mm64<2, 8>(S1, w2, 1024, c * 256, acc2, wid * 2, lane);
                __syncthreads();
            }
#pragma unroll
            for (int i = 0; i < 2; ++i)
#pragma unroll
                for (int m = 0; m < 4; ++m)
#pragma unroll
                    for (int r = 0; r < 4; ++r) xr[m][r][i] += acc2[i][m][r];
        }
        ln_reg(xr, ln2s + l * 256, ln2b + l * 256, xb, red, mrow, srow, tid, fl, fh, wid);
    }

    // ---- masked mean over chars (f32, shuffle over fh) -> NE[w2n*8+wpos] ----
#pragma unroll
    for (int m = 0; m < 4; ++m) {
        int cnt = 0;
#pragma unroll
        for (int c = 0; c < 16; ++c) if (ch[m * 16 + c] != 0) ++cnt;
        float inv = 1.f / (float)cnt;
#pragma unroll
        for (int i = 0; i < 2; ++i) {
            float s = 0.f;
#pragma unroll
            for (int r = 0; r < 4; ++r)
                if (ch[m * 16 + fh * 4 + r] != 0) s += xr[m][r][i];
            s += __shfl_xor(s, 16, 64);
            s += __shfl_xor(s, 32, 64);
            if (fh == 0) {
                int wg = blk * 4 + m;
                size_t nrow = (size_t)w2n[wg] * 8 + wpos[wg];
                NE[nrow * 256 + (wid * 2 + i) * 16 + fl] = s * inv;
            }
        }
    }
}

// =======================================================================================
extern "C" void kernel_launch(void* const* d_in, const int* in_sizes, int n_in,
                              void* d_out, int out_size, void* d_ws, size_t ws_size,
                              hipStream_t stream) {
    float* out = (float*)d_out;

    const int* inputs    = (const int*)d_in[0];
    const int* w2n       = (const int*)d_in[1];
    const int* wpos      = (const int*)d_in[2];
    const float* char_emb = (const float*)d_in[3];
    const float* pos_emb  = (const float*)d_in[4];
    const float* we_Wqkv = (const float*)d_in[5];
    const float* we_Wo   = (const float*)d_in[6];
    const float* we_ln1s = (const float*)d_in[7];
    const float* we_ln1b = (const float*)d_in[8];
    const float* we_W1   = (const float*)d_in[9];
    const float* we_W2   = (const float*)d_in[10];
    const float* we_ln2s = (const float*)d_in[11];
    const float* we_ln2b = (const float*)d_in[12];
    const float* ne_Wqkv = (const float*)d_in[13];
    const float* ne_Wo   = (const float*)d_in[14];
    const float* ne_ln1s = (const float*)d_in[15];
    const float* ne_ln1b = (const float*)d_in[16];
    const float* ne_W1   = (const float*)d_in[17];
    const float* ne_W2   = (const float*)d_in[18];
    const float* ne_ln2s = (const float*)d_in[19];
    const float* ne_ln2b = (const float*)d_in[20];

    char* ws = (char*)d_ws;
    size_t off = 0;
    auto alloc = [&](size_t bytes) { void* p = ws + off; off += (bytes + 255) & ~(size_t)255; return p; };
    float* NE = (float*)alloc((size_t)16384 * 256 * 4);
    unsigned short* qkvT_we = (unsigned short*)alloc((size_t)2 * 196608 * 2);
    unsigned short* woT_we  = (unsigned short*)alloc((size_t)2 * 65536 * 2);
    unsigned short* w1T_we  = (unsigned short*)alloc((size_t)2 * 262144 * 2);
    unsigned short* w2T_we  = (unsigned short*)alloc((size_t)2 * 262144 * 2);
    unsigned short* qkvT_ne = (unsigned short*)alloc((size_t)2 * 196608 * 2);
    unsigned short* woT_ne  = (unsigned short*)alloc((size_t)2 * 65536 * 2);
    unsigned short* w1T_ne  = (unsigned short*)alloc((size_t)2 * 262144 * 2);
    unsigned short* w2T_ne  = (unsigned short*)alloc((size_t)2 * 262144 * 2);

    for (int l = 0; l < 2; ++l) {
        k_wt<<<(196608 + 255) / 256, 256, 0, stream>>>(we_Wqkv + (size_t)l * 196608, qkvT_we + (size_t)l * 196608, 256, 768);
        k_wt<<<(65536  + 255) / 256, 256, 0, stream>>>(we_Wo   + (size_t)l * 65536,  woT_we  + (size_t)l * 65536,  256, 256);
        k_wt<<<(262144 + 255) / 256, 256, 0, stream>>>(we_W1   + (size_t)l * 262144, w1T_we  + (size_t)l * 262144, 256, 1024);
        k_wt<<<(262144 + 255) / 256, 256, 0, stream>>>(we_W2   + (size_t)l * 262144, w2T_we  + (size_t)l * 262144, 1024, 256);
        k_wt<<<(196608 + 255) / 256, 256, 0, stream>>>(ne_Wqkv + (size_t)l * 196608, qkvT_ne + (size_t)l * 196608, 256, 768);
        k_wt<<<(65536  + 255) / 256, 256, 0, stream>>>(ne_Wo   + (size_t)l * 65536,  woT_ne  + (size_t)l * 65536,  256, 256);
        k_wt<<<(262144 + 255) / 256, 256, 0, stream>>>(ne_W1   + (size_t)l * 262144, w1T_ne  + (size_t)l * 262144, 256, 1024);
        k_wt<<<(262144 + 255) / 256, 256, 0, stream>>>(ne_W2   + (size_t)l * 262144, w2T_ne  + (size_t)l * 262144, 1024, 256);
    }

    (void)hipMemsetAsync(NE, 0, (size_t)16384 * 256 * 4, stream);

    // WORD stage: batched M=64, f32 register residual (under test)
    k_word_v2<<<2304, 512, 0, stream>>>(inputs, char_emb, pos_emb,
                                        qkvT_we, woT_we, w1T_we, w2T_we,
                                        we_ln1s, we_ln1b, we_ln2s, we_ln2b,
                                        w2n, wpos, NE);

    // NAME stage: R11-proven kernel
    k_enc_ref<8, false><<<2048, 256, 0, stream>>>(nullptr, nullptr, nullptr,
                                                  qkvT_ne, woT_ne, w1T_ne, w2T_ne,
                                                  ne_ln1s, ne_ln1b, ne_ln2s, ne_ln2b,
                                                  nullptr, nullptr, NE, out);
}

// Round 17
// 1552.941 us; speedup vs baseline: 39.2948x; 1.4201x over previous
//
#include <hip/hip_runtime.h>
#include <hip/hip_bf16.h>

using short8 = __attribute__((ext_vector_type(8))) short;
using f32x4  = __attribute__((ext_vector_type(4))) float;

#define DEV __device__ __forceinline__
#define LDB 264

DEV float bu(unsigned short u) { union { unsigned int i; float f; } z; z.i = (unsigned)u << 16; return z.f; }
DEV unsigned short fb(float f) { __hip_bfloat16 h = __float2bfloat16(f); return *reinterpret_cast<unsigned short*>(&h); }

DEV float gelu_f(float v) {
    float u = 0.7978845608028654f * (v + 0.044715f * v * v * v);
    u = fminf(fmaxf(u, -20.f), 20.f);
    float e = __expf(2.f * u);                 // tanh(u) = (e^{2u}-1)/(e^{2u}+1)
    return 0.5f * v * (1.f + (e - 1.f) / (e + 1.f));
}

// ---------------- weight prep: WT[n][k] = bf16(W[k][n]) ----------------
__global__ void k_wt(const float* __restrict__ W, unsigned short* __restrict__ WT, int K, int N) {
    int i = blockIdx.x * 256 + threadIdx.x;
    if (i >= N * K) return;
    int n = i / K, k = i % K;
    WT[i] = fb(W[(size_t)k * N + n]);
}

// ---------------------------------------------------------------------------------------
// Per-wave MFMA: acc[NT][4] += A[64][K](bf16 LDS, ld LDB) @ B[rows=(nt0+i)*16+fl][ldB]^T
// A-frag: row=m*16+fl, k=fh*8+j. D: row=m*16+fh*4+r, col=(nt0+i)*16+fl  [m89-verified].
// ---------------------------------------------------------------------------------------
template<int NT, int KG>
DEV void mm64(const unsigned short* __restrict__ A, const unsigned short* __restrict__ B,
              int ldB, int koff, f32x4 acc[NT][4], int nt0, int lane)
{
    const int fl = lane & 15, fh = lane >> 4;
#pragma unroll
    for (int kg = 0; kg < KG; ++kg) {
        short8 b[NT];
#pragma unroll
        for (int i = 0; i < NT; ++i)
            b[i] = *(const short8*)(B + (size_t)((nt0 + i) * 16 + fl) * ldB + koff + kg * 32 + fh * 8);
        short8 a[4];
#pragma unroll
        for (int m = 0; m < 4; ++m)
            a[m] = *(const short8*)(A + (m * 16 + fl) * LDB + kg * 32 + fh * 8);
#pragma unroll
        for (int i = 0; i < NT; ++i)
#pragma unroll
            for (int m = 0; m < 4; ++m)
                acc[i][m] = __builtin_amdgcn_mfma_f32_16x16x32_bf16(a[m], b[i], acc[i][m], 0, 0, 0);
    }
}

template<int NT, bool GEL>
DEV void store_bf16(f32x4 acc[NT][4], unsigned short* __restrict__ D, int nt0, int lane) {
    const int fl = lane & 15, r0 = (lane >> 4) * 4;
#pragma unroll
    for (int i = 0; i < NT; ++i)
#pragma unroll
        for (int m = 0; m < 4; ++m)
#pragma unroll
            for (int r = 0; r < 4; ++r) {
                float v = acc[i][m][r];
                if (GEL) v = gelu_f(v);
                D[(m * 16 + r0 + r) * LDB + (nt0 + i) * 16 + fl] = fb(v);
            }
}

// f32 LayerNorm over register-resident xr; stats via shfl + red[64][8]; writes bf16 xb.
DEV void ln_reg(float xr[4][4][2], const float* __restrict__ s, const float* __restrict__ b,
                unsigned short* __restrict__ xb, float red[64][8],
                float* mrow, float* srow, int tid, int fl, int fh, int wid)
{
    float ps[4][4];
#pragma unroll
    for (int m = 0; m < 4; ++m)
#pragma unroll
        for (int r = 0; r < 4; ++r) {
            float v = xr[m][r][0] + xr[m][r][1];
#pragma unroll
            for (int off = 8; off >= 1; off >>= 1) v += __shfl_xor(v, off, 64);
            ps[m][r] = v;
        }
    if (fl == 0)
#pragma unroll
        for (int m = 0; m < 4; ++m)
#pragma unroll
            for (int r = 0; r < 4; ++r) red[m * 16 + fh * 4 + r][wid] = ps[m][r];
    __syncthreads();
    if (tid < 64) {
        float sum = 0.f;
#pragma unroll
        for (int j = 0; j < 8; ++j) sum += red[tid][j];
        mrow[tid] = sum * (1.f / 256.f);
    }
    __syncthreads();
#pragma unroll
    for (int m = 0; m < 4; ++m)
#pragma unroll
        for (int r = 0; r < 4; ++r) {
            float mu = mrow[m * 16 + fh * 4 + r];
            float d0 = xr[m][r][0] - mu, d1 = xr[m][r][1] - mu;
            float v = d0 * d0 + d1 * d1;
#pragma unroll
            for (int off = 8; off >= 1; off >>= 1) v += __shfl_xor(v, off, 64);
            ps[m][r] = v;
        }
    if (fl == 0)
#pragma unroll
        for (int m = 0; m < 4; ++m)
#pragma unroll
            for (int r = 0; r < 4; ++r) red[m * 16 + fh * 4 + r][wid] = ps[m][r];
    __syncthreads();
    if (tid < 64) {
        float sum = 0.f;
#pragma unroll
        for (int j = 0; j < 8; ++j) sum += red[tid][j];
        srow[tid] = rsqrtf(sum * (1.f / 256.f) + 1e-5f);
    }
    __syncthreads();
    float sc[2], bc[2];
#pragma unroll
    for (int i = 0; i < 2; ++i) { int c = (wid * 2 + i) * 16 + fl; sc[i] = s[c]; bc[i] = b[c]; }
#pragma unroll
    for (int m = 0; m < 4; ++m)
#pragma unroll
        for (int r = 0; r < 4; ++r) {
            int row = m * 16 + fh * 4 + r;
            float mu = mrow[row], rs = srow[row];
#pragma unroll
            for (int i = 0; i < 2; ++i) {
                float v = (xr[m][r][i] - mu) * rs * sc[i] + bc[i];
                xr[m][r][i] = v;
                xb[row * LDB + (wid * 2 + i) * 16 + fl] = fb(v);
            }
        }
    __syncthreads();
}

// ---------------------------------------------------------------------------------------
// Fused 2-layer encoder, M=64 rows/block, f32 register residual.
// WORD=1: 4 words x 16 chars, key-pad mask, epilogue = masked char-mean -> NE scatter.
// WORD=0: 8 names x 8 slots (reads f32 NE), epilogue = np2-masked slot-mean -> out.
// ---------------------------------------------------------------------------------------
template<bool WORD>
__global__ __launch_bounds__(512, 1) void k_enc64(
    const int* __restrict__ inputs,
    const float* __restrict__ char_emb, const float* __restrict__ pos_emb,
    const unsigned short* __restrict__ qkvT, const unsigned short* __restrict__ woT,
    const unsigned short* __restrict__ w1T,  const unsigned short* __restrict__ w2T,
    const float* __restrict__ ln1s, const float* __restrict__ ln1b,
    const float* __restrict__ ln2s, const float* __restrict__ ln2b,
    const int* __restrict__ w2n, const int* __restrict__ wpos,
    float* __restrict__ NE, float* __restrict__ out)
{
    constexpr int T = WORD ? 16 : 8;
    const int blk = blockIdx.x, tid = threadIdx.x;
    const int lane = tid & 63, wid = tid >> 6;
    const int fl = lane & 15, fh = lane >> 4;
    __shared__ __attribute__((aligned(16))) unsigned short xb[64 * LDB];  // bf16 A-operand
    __shared__ __attribute__((aligned(16))) unsigned short S1[64 * LDB];  // Q / V / ff-hidden
    __shared__ __attribute__((aligned(16))) unsigned short S2[64 * LDB];  // K / attn-out
    __shared__ float red[64][8];
    __shared__ float mrow[64], srow[64];
    __shared__ int ch[64];

    // attention mapping: WORD: 4 words x 8 heads x 16 q; NAME: 8 names x 8 heads x 8 q
    const int wl = WORD ? (tid >> 7) : (tid >> 6);
    const int hh = WORD ? ((tid >> 4) & 7) : ((tid >> 3) & 7);
    const int tt = WORD ? (tid & 15) : (tid & 7);
    const int arow = wl * T + tt;

    float xr[4][4][2];   // f32 residual stream (this thread's MFMA D-fragment cells)

    if (WORD) {
        if (tid < 64) ch[tid] = inputs[blk * 64 + tid];
        __syncthreads();
#pragma unroll
        for (int m = 0; m < 4; ++m)
#pragma unroll
            for (int r = 0; r < 4; ++r) {
                int row = m * 16 + fh * 4 + r;
#pragma unroll
                for (int i = 0; i < 2; ++i) {
                    int col = (wid * 2 + i) * 16 + fl;
                    float v = char_emb[(size_t)ch[row] * 256 + col] + pos_emb[(row & 15) * 256 + col];
                    xr[m][r][i] = v;
                    xb[row * LDB + col] = fb(v);
                }
            }
    } else {
#pragma unroll
        for (int m = 0; m < 4; ++m)
#pragma unroll
            for (int r = 0; r < 4; ++r) {
                int row = m * 16 + fh * 4 + r;
#pragma unroll
                for (int i = 0; i < 2; ++i) {
                    int col = (wid * 2 + i) * 16 + fl;
                    float v = NE[((size_t)blk * 64 + row) * 256 + col];
                    xr[m][r][i] = v;
                    xb[row * LDB + col] = fb(v);
                }
            }
    }
    __syncthreads();

    for (int l = 0; l < 2; ++l) {
        const unsigned short* wq = qkvT + (size_t)l * 196608;
        const unsigned short* wk = wq + 65536;
        const unsigned short* wv = wq + 131072;
        const unsigned short* wo = woT + (size_t)l * 65536;
        const unsigned short* w1 = w1T + (size_t)l * 262144;
        const unsigned short* w2 = w2T + (size_t)l * 262144;

        // ---- Q->S1, K->S2 ----
        { f32x4 acc[2][4] = {}; mm64<2, 8>(xb, wq, 256, 0, acc, wid * 2, lane); store_bf16<2, false>(acc, S1, wid * 2, lane); }
        { f32x4 acc[2][4] = {}; mm64<2, 8>(xb, wk, 256, 0, acc, wid * 2, lane); store_bf16<2, false>(acc, S2, wid * 2, lane); }
        __syncthreads();

        // ---- q -> regs (vector loads); scores+softmax from S2(K) ----
        float q[32], p[T];
        {
#pragma unroll
            for (int db = 0; db < 4; ++db) {
                short8 qv = *(const short8*)&S1[arow * LDB + hh * 32 + db * 8];
#pragma unroll
                for (int j = 0; j < 8; ++j) q[db * 8 + j] = bu((unsigned short)qv[j]);
            }
            float mx = -1e30f;
#pragma unroll
            for (int s = 0; s < T; ++s) {
                float dot = 0.f;
#pragma unroll
                for (int db = 0; db < 4; ++db) {
                    short8 kv = *(const short8*)&S2[(wl * T + s) * LDB + hh * 32 + db * 8];
#pragma unroll
                    for (int j = 0; j < 8; ++j) dot += q[db * 8 + j] * bu((unsigned short)kv[j]);
                }
                dot *= 0.17677669529663687f;             // 1/sqrt(32)
                if (WORD && ch[wl * 16 + s] == 0) dot = -1e9f;   // key-pad mask
                p[s] = dot; mx = fmaxf(mx, dot);
            }
            float sum = 0.f;
#pragma unroll
            for (int s = 0; s < T; ++s) { p[s] = __expf(p[s] - mx); sum += p[s]; }
            float inv = 1.f / sum;
#pragma unroll
            for (int s = 0; s < T; ++s) p[s] *= inv;
        }
        __syncthreads();                                  // all q loaded; S1 free

        // ---- V->S1 (q already in regs) ----
        { f32x4 acc[2][4] = {}; mm64<2, 8>(xb, wv, 256, 0, acc, wid * 2, lane); store_bf16<2, false>(acc, S1, wid * 2, lane); }
        __syncthreads();

        // ---- PV from S1(V) -> o into S2 (vector loads+stores; own-cell race-free) ----
        {
            float o[32];
#pragma unroll
            for (int j = 0; j < 32; ++j) o[j] = 0.f;
#pragma unroll
            for (int s = 0; s < T; ++s) {
                float ps = p[s];
#pragma unroll
                for (int db = 0; db < 4; ++db) {
                    short8 vv = *(const short8*)&S1[(wl * T + s) * LDB + hh * 32 + db * 8];
#pragma unroll
                    for (int j = 0; j < 8; ++j) o[db * 8 + j] += ps * bu((unsigned short)vv[j]);
                }
            }
#pragma unroll
            for (int db = 0; db < 4; ++db) {
                short8 ov;
#pragma unroll
                for (int j = 0; j < 8; ++j) ov[j] = (short)fb(o[db * 8 + j]);
                *(short8*)&S2[arow * LDB + hh * 32 + db * 8] = ov;
            }
        }
        __syncthreads();

        // ---- Wo: S2(o) @ wo ; residual add in f32 regs; LN1 ----
        { f32x4 acc[2][4] = {}; mm64<2, 8>(S2, wo, 256, 0, acc, wid * 2, lane);
#pragma unroll
          for (int i = 0; i < 2; ++i)
#pragma unroll
              for (int m = 0; m < 4; ++m)
#pragma unroll
                  for (int r = 0; r < 4; ++r) xr[m][r][i] += acc[i][m][r]; }
        __syncthreads();
        ln_reg(xr, ln1s + l * 256, ln1b + l * 256, xb, red, mrow, srow, tid, fl, fh, wid);

        // ---- FF: 4 hidden chunks; FF2 accumulates f32; residual; LN2 ----
        {
            f32x4 acc2[2][4] = {};
            for (int c = 0; c < 4; ++c) {
                f32x4 acc1[2][4] = {};
                mm64<2, 8>(xb, w1 + (size_t)c * 65536, 256, 0, acc1, wid * 2, lane);
                store_bf16<2, true>(acc1, S1, wid * 2, lane);      // gelu(hidden chunk)
                __syncthreads();
                mm64<2, 8>(S1, w2, 1024, c * 256, acc2, wid * 2, lane);
                __syncthreads();
            }
#pragma unroll
            for (int i = 0; i < 2; ++i)
#pragma unroll
                for (int m = 0; m < 4; ++m)
#pragma unroll
                    for (int r = 0; r < 4; ++r) xr[m][r][i] += acc2[i][m][r];
        }
        ln_reg(xr, ln2s + l * 256, ln2b + l * 256, xb, red, mrow, srow, tid, fl, fh, wid);
    }

    if (WORD) {
        // masked mean over chars (f32, shuffle over fh) -> NE[w2n*8+wpos]
#pragma unroll
        for (int m = 0; m < 4; ++m) {
            int cnt = 0;
#pragma unroll
            for (int c = 0; c < 16; ++c) if (ch[m * 16 + c] != 0) ++cnt;
            float inv = 1.f / (float)cnt;
#pragma unroll
            for (int i = 0; i < 2; ++i) {
                float s = 0.f;
#pragma unroll
                for (int r = 0; r < 4; ++r)
                    if (ch[m * 16 + fh * 4 + r] != 0) s += xr[m][r][i];
                s += __shfl_xor(s, 16, 64);
                s += __shfl_xor(s, 32, 64);
                if (fh == 0) {
                    int wg = blk * 4 + m;
                    size_t nrow = (size_t)w2n[wg] * 8 + wpos[wg];
                    NE[nrow * 256 + (wid * 2 + i) * 16 + fl] = s * inv;
                }
            }
        }
    } else {
        // np2-masked mean over 8 slots (pristine NE) -> out
        // thread rows m*16+fh*4+r: name-in-block = 2m+(fh>>1), slots (fh*4+r)&7
#pragma unroll
        for (int m = 0; m < 4; ++m)
#pragma unroll
            for (int i = 0; i < 2; ++i) {
                int col = (wid * 2 + i) * 16 + fl;
                float s = 0.f, c = 0.f;
#pragma unroll
                for (int r = 0; r < 4; ++r) {
                    int row = m * 16 + fh * 4 + r;
                    float nev = NE[((size_t)blk * 64 + row) * 256 + col];
                    if (nev != 0.f) { s += xr[m][r][i]; c += 1.f; }
                }
                s += __shfl_xor(s, 16, 64);              // fh pairs {0,1},{2,3}: full 8 slots
                c += __shfl_xor(c, 16, 64);
                if ((fh & 1) == 0) {
                    int name = blk * 8 + 2 * m + (fh >> 1);
                    out[(size_t)name * 256 + col] = (c > 0.f) ? s / c : 0.f;
                }
            }
    }
}

// =======================================================================================
extern "C" void kernel_launch(void* const* d_in, const int* in_sizes, int n_in,
                              void* d_out, int out_size, void* d_ws, size_t ws_size,
                              hipStream_t stream) {
    float* out = (float*)d_out;

    const int* inputs    = (const int*)d_in[0];
    const int* w2n       = (const int*)d_in[1];
    const int* wpos      = (const int*)d_in[2];
    const float* char_emb = (const float*)d_in[3];
    const float* pos_emb  = (const float*)d_in[4];
    const float* we_Wqkv = (const float*)d_in[5];
    const float* we_Wo   = (const float*)d_in[6];
    const float* we_ln1s = (const float*)d_in[7];
    const float* we_ln1b = (const float*)d_in[8];
    const float* we_W1   = (const float*)d_in[9];
    const float* we_W2   = (const float*)d_in[10];
    const float* we_ln2s = (const float*)d_in[11];
    const float* we_ln2b = (const float*)d_in[12];
    const float* ne_Wqkv = (const float*)d_in[13];
    const float* ne_Wo   = (const float*)d_in[14];
    const float* ne_ln1s = (const float*)d_in[15];
    const float* ne_ln1b = (const float*)d_in[16];
    const float* ne_W1   = (const float*)d_in[17];
    const float* ne_W2   = (const float*)d_in[18];
    const float* ne_ln2s = (const float*)d_in[19];
    const float* ne_ln2b = (const float*)d_in[20];

    char* ws = (char*)d_ws;
    size_t off = 0;
    auto alloc = [&](size_t bytes) { void* p = ws + off; off += (bytes + 255) & ~(size_t)255; return p; };
    float* NE = (float*)alloc((size_t)16384 * 256 * 4);
    unsigned short* qkvT_we = (unsigned short*)alloc((size_t)2 * 196608 * 2);
    unsigned short* woT_we  = (unsigned short*)alloc((size_t)2 * 65536 * 2);
    unsigned short* w1T_we  = (unsigned short*)alloc((size_t)2 * 262144 * 2);
    unsigned short* w2T_we  = (unsigned short*)alloc((size_t)2 * 262144 * 2);
    unsigned short* qkvT_ne = (unsigned short*)alloc((size_t)2 * 196608 * 2);
    unsigned short* woT_ne  = (unsigned short*)alloc((size_t)2 * 65536 * 2);
    unsigned short* w1T_ne  = (unsigned short*)alloc((size_t)2 * 262144 * 2);
    unsigned short* w2T_ne  = (unsigned short*)alloc((size_t)2 * 262144 * 2);

    for (int l = 0; l < 2; ++l) {
        k_wt<<<(196608 + 255) / 256, 256, 0, stream>>>(we_Wqkv + (size_t)l * 196608, qkvT_we + (size_t)l * 196608, 256, 768);
        k_wt<<<(65536  + 255) / 256, 256, 0, stream>>>(we_Wo   + (size_t)l * 65536,  woT_we  + (size_t)l * 65536,  256, 256);
        k_wt<<<(262144 + 255) / 256, 256, 0, stream>>>(we_W1   + (size_t)l * 262144, w1T_we  + (size_t)l * 262144, 256, 1024);
        k_wt<<<(262144 + 255) / 256, 256, 0, stream>>>(we_W2   + (size_t)l * 262144, w2T_we  + (size_t)l * 262144, 1024, 256);
        k_wt<<<(196608 + 255) / 256, 256, 0, stream>>>(ne_Wqkv + (size_t)l * 196608, qkvT_ne + (size_t)l * 196608, 256, 768);
        k_wt<<<(65536  + 255) / 256, 256, 0, stream>>>(ne_Wo   + (size_t)l * 65536,  woT_ne  + (size_t)l * 65536,  256, 256);
        k_wt<<<(262144 + 255) / 256, 256, 0, stream>>>(ne_W1   + (size_t)l * 262144, w1T_ne  + (size_t)l * 262144, 256, 1024);
        k_wt<<<(262144 + 255) / 256, 256, 0, stream>>>(ne_W2   + (size_t)l * 262144, w2T_ne  + (size_t)l * 262144, 1024, 256);
    }

    (void)hipMemsetAsync(NE, 0, (size_t)16384 * 256 * 4, stream);

    // WORD stage: batched M=64, f32 register residual (proven R16)
    k_enc64<true><<<2304, 512, 0, stream>>>(inputs, char_emb, pos_emb,
                                            qkvT_we, woT_we, w1T_we, w2T_we,
                                            we_ln1s, we_ln1b, we_ln2s, we_ln2b,
                                            w2n, wpos, NE, nullptr);

    // NAME stage: batched M=64 (8 names/block), same structure
    k_enc64<false><<<256, 512, 0, stream>>>(nullptr, nullptr, nullptr,
                                            qkvT_ne, woT_ne, w1T_ne, w2T_ne,
                                            ne_ln1s, ne_ln1b, ne_ln2s, ne_ln2b,
                                            nullptr, nullptr, NE, out);
}